// Round 1
// baseline (1434.862 us; speedup 1.0000x reference)
//
#include <hip/hip_runtime.h>
#include <hip/hip_bf16.h>
#include <cstdint>
#include <cstddef>

#define NTOK 4096
#define EMB 1024
#define HID 4096
#define NEXP 8
#define LDP 40   // LDS row stride (bf16 elems): 32 + 8 pad -> 20-bank rotation, 2-way free

typedef __bf16 bf16x8_t __attribute__((ext_vector_type(8)));
typedef __bf16 bf16x4_t __attribute__((ext_vector_type(4)));
typedef float  f32x4_t  __attribute__((ext_vector_type(4)));

// ---------------- router: scores, top-2, softmax, aux stats ----------------
__global__ __launch_bounds__(64) void router_kernel(
    const float* __restrict__ x, const float* __restrict__ gw,
    int* __restrict__ counts, float* __restrict__ probsum,
    int* __restrict__ topk_idx, float* __restrict__ topk_prob)
{
    const int t = blockIdx.x;
    const int lane = threadIdx.x;
    const float* xr = x + (size_t)t * EMB;
    float xv[16];
#pragma unroll
    for (int i = 0; i < 16; i++) xv[i] = xr[lane + 64 * i];
    float sc[8];
#pragma unroll
    for (int e = 0; e < 8; e++) {
        const float* g = gw + (size_t)e * EMB;
        float a = 0.f;
#pragma unroll
        for (int i = 0; i < 16; i++) a += xv[i] * g[lane + 64 * i];
        sc[e] = a;
    }
#pragma unroll
    for (int off = 32; off > 0; off >>= 1) {
#pragma unroll
        for (int e = 0; e < 8; e++) sc[e] += __shfl_xor(sc[e], off, 64);
    }
    if (lane == 0) {
        int j0 = 0; float s0 = sc[0];
        for (int e = 1; e < 8; e++) if (sc[e] > s0) { s0 = sc[e]; j0 = e; }
        int j1 = -1; float s1 = -1e30f;
        for (int e = 0; e < 8; e++) if (e != j0 && sc[e] > s1) { s1 = sc[e]; j1 = e; }
        float r = __expf(s1 - s0);          // s1 <= s0
        float p0 = 1.0f / (1.0f + r);
        float p1 = r * p0;
        topk_idx[2 * t] = j0;  topk_idx[2 * t + 1] = j1;
        topk_prob[2 * t] = p0; topk_prob[2 * t + 1] = p1;
        atomicAdd(&counts[j0], 1);
        atomicAdd(&counts[j1], 1);
        float pe[8]; float sum = 0.f;
        for (int e = 0; e < 8; e++) { pe[e] = __expf(sc[e] - s0); sum += pe[e]; }
        float inv = 1.0f / sum;
        for (int e = 0; e < 8; e++) atomicAdd(&probsum[e], pe[e] * inv);
    }
}

// ---------------- scan: offsets + aux loss ----------------
__global__ void scan_kernel(const int* __restrict__ counts, const float* __restrict__ probsum,
                            int* __restrict__ offsets, float* __restrict__ aux_out)
{
    if (threadIdx.x == 0 && blockIdx.x == 0) {
        int off = 0; float aux = 0.f;
        for (int e = 0; e < 8; e++) {
            offsets[e] = off;
            off += counts[e];
            aux += (float)counts[e] * probsum[e];
        }
        *aux_out = aux * 8.0f / ((float)NTOK * (float)NTOK);
    }
}

// ---------------- scatter tokens into expert segments ----------------
__global__ void scatter_kernel(const int* __restrict__ topk_idx, const float* __restrict__ topk_prob,
                               const int* __restrict__ offsets, int* __restrict__ cursor,
                               int* __restrict__ row_tok, float* __restrict__ row_prob)
{
    int t = blockIdx.x * blockDim.x + threadIdx.x;
    if (t >= NTOK) return;
    for (int k = 0; k < 2; k++) {
        int e = topk_idx[2 * t + k];
        int pos = offsets[e] + atomicAdd(&cursor[e], 1);
        row_tok[pos] = t;
        row_prob[pos] = topk_prob[2 * t + k];
    }
}

// ---------------- x fp32 -> bf16 ----------------
__global__ void cvt_x_kernel(const float* __restrict__ x, __bf16* __restrict__ xbf)
{
    int i = blockIdx.x * 256 + threadIdx.x;   // 4 elems each
    float4 v = ((const float4*)x)[i];
    bf16x4_t o;
    o[0] = (__bf16)v.x; o[1] = (__bf16)v.y; o[2] = (__bf16)v.z; o[3] = (__bf16)v.w;
    *(bf16x4_t*)(xbf + (size_t)i * 4) = o;
}

// ---------------- GEMM1: H = silu(Xg W1^T + b1) * (Xg W2^T + b2) ----------------
__global__ __launch_bounds__(256, 2) void gemm1_kernel(
    const __bf16* __restrict__ xbf,
    const float* __restrict__ w1, const float* __restrict__ b1,
    const float* __restrict__ w2, const float* __restrict__ b2,
    const int* __restrict__ counts, const int* __restrict__ offsets,
    const int* __restrict__ row_tok, __bf16* __restrict__ Hbuf)
{
    const int e = blockIdx.z;
    const int cnt = counts[e];
    const int row0 = blockIdx.y * 128;
    if (row0 >= cnt) return;
    const int seg = offsets[e];
    const int n0 = blockIdx.x * 128;

    __shared__ __align__(16) __bf16 As[128][LDP];
    __shared__ __align__(16) __bf16 Bs1[128][LDP];
    __shared__ __align__(16) __bf16 Bs2[128][LDP];

    const int tid = threadIdx.x;
    const int sr = tid >> 1;     // staging row 0..127
    const int sh = tid & 1;      // staging half (16 elems each)

    const uint4* ap = nullptr;
    if (row0 + sr < cnt) {
        const int tok = row_tok[seg + row0 + sr];
        ap = (const uint4*)(xbf + (size_t)tok * EMB) + sh * 2;
    }
    const float4* b1p = (const float4*)(w1 + ((size_t)e * HID + n0 + sr) * EMB) + sh * 4;
    const float4* b2p = (const float4*)(w2 + ((size_t)e * HID + n0 + sr) * EMB) + sh * 4;

    const int lane = tid & 63;
    const int wave = tid >> 6;
    const int wm = (wave >> 1) * 64;
    const int wn = (wave & 1) * 64;
    const int fr = lane & 15;
    const int quad = lane >> 4;

    f32x4_t acc1[4][4], acc2[4][4];
#pragma unroll
    for (int i = 0; i < 4; i++)
#pragma unroll
        for (int j = 0; j < 4; j++)
#pragma unroll
            for (int c = 0; c < 4; c++) { acc1[i][j][c] = 0.f; acc2[i][j][c] = 0.f; }

    for (int kk = 0; kk < EMB; kk += 32) {
        uint4 a0 = {0,0,0,0}, a1 = {0,0,0,0};
        if (ap) { a0 = ap[0]; a1 = ap[1]; ap += 4; }
        float4 f10 = b1p[0], f11 = b1p[1], f12 = b1p[2], f13 = b1p[3]; b1p += 8;
        float4 f20 = b2p[0], f21 = b2p[1], f22 = b2p[2], f23 = b2p[3]; b2p += 8;

        __syncthreads();
        *(uint4*)&As[sr][sh * 16]     = a0;
        *(uint4*)&As[sr][sh * 16 + 8] = a1;

        bf16x8_t p;
        p[0]=(__bf16)f10.x; p[1]=(__bf16)f10.y; p[2]=(__bf16)f10.z; p[3]=(__bf16)f10.w;
        p[4]=(__bf16)f11.x; p[5]=(__bf16)f11.y; p[6]=(__bf16)f11.z; p[7]=(__bf16)f11.w;
        *(bf16x8_t*)&Bs1[sr][sh * 16] = p;
        p[0]=(__bf16)f12.x; p[1]=(__bf16)f12.y; p[2]=(__bf16)f12.z; p[3]=(__bf16)f12.w;
        p[4]=(__bf16)f13.x; p[5]=(__bf16)f13.y; p[6]=(__bf16)f13.z; p[7]=(__bf16)f13.w;
        *(bf16x8_t*)&Bs1[sr][sh * 16 + 8] = p;

        p[0]=(__bf16)f20.x; p[1]=(__bf16)f20.y; p[2]=(__bf16)f20.z; p[3]=(__bf16)f20.w;
        p[4]=(__bf16)f21.x; p[5]=(__bf16)f21.y; p[6]=(__bf16)f21.z; p[7]=(__bf16)f21.w;
        *(bf16x8_t*)&Bs2[sr][sh * 16] = p;
        p[0]=(__bf16)f22.x; p[1]=(__bf16)f22.y; p[2]=(__bf16)f22.z; p[3]=(__bf16)f22.w;
        p[4]=(__bf16)f23.x; p[5]=(__bf16)f23.y; p[6]=(__bf16)f23.z; p[7]=(__bf16)f23.w;
        *(bf16x8_t*)&Bs2[sr][sh * 16 + 8] = p;
        __syncthreads();

        bf16x8_t av[4], bv1[4], bv2[4];
#pragma unroll
        for (int i = 0; i < 4; i++) av[i]  = *(const bf16x8_t*)&As [wm + i * 16 + fr][quad * 8];
#pragma unroll
        for (int j = 0; j < 4; j++) bv1[j] = *(const bf16x8_t*)&Bs1[wn + j * 16 + fr][quad * 8];
#pragma unroll
        for (int j = 0; j < 4; j++) bv2[j] = *(const bf16x8_t*)&Bs2[wn + j * 16 + fr][quad * 8];
#pragma unroll
        for (int i = 0; i < 4; i++)
#pragma unroll
            for (int j = 0; j < 4; j++) {
                acc1[i][j] = __builtin_amdgcn_mfma_f32_16x16x32_bf16(av[i], bv1[j], acc1[i][j], 0, 0, 0);
                acc2[i][j] = __builtin_amdgcn_mfma_f32_16x16x32_bf16(av[i], bv2[j], acc2[i][j], 0, 0, 0);
            }
    }

    // epilogue: h = silu(c1 + b1) * (c2 + b2), store bf16
    float b1v[4], b2v[4];
#pragma unroll
    for (int j = 0; j < 4; j++) {
        int nn = n0 + wn + j * 16 + fr;
        b1v[j] = b1[(size_t)e * HID + nn];
        b2v[j] = b2[(size_t)e * HID + nn];
    }
#pragma unroll
    for (int i = 0; i < 4; i++) {
#pragma unroll
        for (int rr = 0; rr < 4; rr++) {
            int grow = row0 + wm + i * 16 + quad * 4 + rr;
            if (grow < cnt) {
                __bf16* hrow = Hbuf + (size_t)(seg + grow) * HID;
#pragma unroll
                for (int j = 0; j < 4; j++) {
                    float c1 = acc1[i][j][rr] + b1v[j];
                    float c2 = acc2[i][j][rr] + b2v[j];
                    float sig = 1.0f / (1.0f + __expf(-c1));
                    hrow[n0 + wn + j * 16 + fr] = (__bf16)(c1 * sig * c2);
                }
            }
        }
    }
}

// ---------------- GEMM2: out += p * (H W3^T + b3) ----------------
__global__ __launch_bounds__(256, 2) void gemm2_kernel(
    const __bf16* __restrict__ Hbuf,
    const float* __restrict__ w3, const float* __restrict__ b3,
    const int* __restrict__ counts, const int* __restrict__ offsets,
    const int* __restrict__ row_tok, const float* __restrict__ row_prob,
    float* __restrict__ out)
{
    const int e = blockIdx.z;
    const int cnt = counts[e];
    const int row0 = blockIdx.y * 128;
    if (row0 >= cnt) return;
    const int seg = offsets[e];
    const int n0 = blockIdx.x * 128;

    __shared__ __align__(16) __bf16 As[128][LDP];
    __shared__ __align__(16) __bf16 Bs[128][LDP];

    const int tid = threadIdx.x;
    const int sr = tid >> 1;
    const int sh = tid & 1;

    // Hbuf has 128 rows of slack; reads past cnt are masked in the epilogue
    const uint4* ap = (const uint4*)(Hbuf + (size_t)(seg + row0 + sr) * HID) + sh * 2;
    const float4* bp = (const float4*)(w3 + ((size_t)e * EMB + n0 + sr) * HID) + sh * 4;

    const int lane = tid & 63;
    const int wave = tid >> 6;
    const int wm = (wave >> 1) * 64;
    const int wn = (wave & 1) * 64;
    const int fr = lane & 15;
    const int quad = lane >> 4;

    f32x4_t acc[4][4];
#pragma unroll
    for (int i = 0; i < 4; i++)
#pragma unroll
        for (int j = 0; j < 4; j++)
#pragma unroll
            for (int c = 0; c < 4; c++) acc[i][j][c] = 0.f;

    for (int kk = 0; kk < HID; kk += 32) {
        uint4 a0 = ap[0], a1 = ap[1]; ap += 4;
        float4 f0 = bp[0], f1 = bp[1], f2 = bp[2], f3 = bp[3]; bp += 8;

        __syncthreads();
        *(uint4*)&As[sr][sh * 16]     = a0;
        *(uint4*)&As[sr][sh * 16 + 8] = a1;
        bf16x8_t p;
        p[0]=(__bf16)f0.x; p[1]=(__bf16)f0.y; p[2]=(__bf16)f0.z; p[3]=(__bf16)f0.w;
        p[4]=(__bf16)f1.x; p[5]=(__bf16)f1.y; p[6]=(__bf16)f1.z; p[7]=(__bf16)f1.w;
        *(bf16x8_t*)&Bs[sr][sh * 16] = p;
        p[0]=(__bf16)f2.x; p[1]=(__bf16)f2.y; p[2]=(__bf16)f2.z; p[3]=(__bf16)f2.w;
        p[4]=(__bf16)f3.x; p[5]=(__bf16)f3.y; p[6]=(__bf16)f3.z; p[7]=(__bf16)f3.w;
        *(bf16x8_t*)&Bs[sr][sh * 16 + 8] = p;
        __syncthreads();

        bf16x8_t av[4], bv[4];
#pragma unroll
        for (int i = 0; i < 4; i++) av[i] = *(const bf16x8_t*)&As[wm + i * 16 + fr][quad * 8];
#pragma unroll
        for (int j = 0; j < 4; j++) bv[j] = *(const bf16x8_t*)&Bs[wn + j * 16 + fr][quad * 8];
#pragma unroll
        for (int i = 0; i < 4; i++)
#pragma unroll
            for (int j = 0; j < 4; j++)
                acc[i][j] = __builtin_amdgcn_mfma_f32_16x16x32_bf16(av[i], bv[j], acc[i][j], 0, 0, 0);
    }

    float b3v[4];
#pragma unroll
    for (int j = 0; j < 4; j++) b3v[j] = b3[(size_t)e * EMB + n0 + wn + j * 16 + fr];
#pragma unroll
    for (int i = 0; i < 4; i++) {
#pragma unroll
        for (int rr = 0; rr < 4; rr++) {
            int grow = row0 + wm + i * 16 + quad * 4 + rr;
            if (grow < cnt) {
                int tok = row_tok[seg + grow];
                float pr = row_prob[seg + grow];
                float* orow = out + (size_t)tok * EMB;
#pragma unroll
                for (int j = 0; j < 4; j++) {
                    float v = pr * (acc[i][j][rr] + b3v[j]);
                    atomicAdd(&orow[n0 + wn + j * 16 + fr], v);
                }
            }
        }
    }
}

extern "C" void kernel_launch(void* const* d_in, const int* in_sizes, int n_in,
                              void* d_out, int out_size, void* d_ws, size_t ws_size,
                              hipStream_t stream)
{
    const float* x  = (const float*)d_in[0];
    const float* gw = (const float*)d_in[1];
    const float* w1 = (const float*)d_in[2];
    const float* b1 = (const float*)d_in[3];
    const float* w2 = (const float*)d_in[4];
    const float* b2 = (const float*)d_in[5];
    const float* w3 = (const float*)d_in[6];
    const float* b3 = (const float*)d_in[7];
    float* out = (float*)d_out;

    char* ws = (char*)d_ws;
    int*   counts    = (int*)(ws + 0);        // 8
    float* probsum   = (float*)(ws + 32);     // 8
    int*   cursor    = (int*)(ws + 64);       // 8
    int*   offsets   = (int*)(ws + 96);       // 8
    int*   topk_idx  = (int*)(ws + 128);      // 8192 ints
    float* topk_prob = (float*)(ws + 32896);  // 8192 floats
    int*   row_tok   = (int*)(ws + 65664);    // 8192 ints
    float* row_prob  = (float*)(ws + 98432);  // 8192 floats
    __bf16* xbf  = (__bf16*)(ws + 131328);              // 4096*1024 bf16 = 8 MB
    __bf16* Hbuf = (__bf16*)(ws + 131328 + 8388608);    // (8192+128)*4096 bf16 = 68.2 MB

    hipMemsetAsync(ws, 0, 128, stream);
    hipMemsetAsync(d_out, 0, (size_t)out_size * sizeof(float), stream);

    cvt_x_kernel<<<dim3((NTOK * EMB) / (256 * 4)), dim3(256), 0, stream>>>(x, xbf);
    router_kernel<<<dim3(NTOK), dim3(64), 0, stream>>>(x, gw, counts, probsum, topk_idx, topk_prob);
    scan_kernel<<<dim3(1), dim3(64), 0, stream>>>(counts, probsum, offsets, out + (size_t)NTOK * EMB);
    scatter_kernel<<<dim3(NTOK / 256), dim3(256), 0, stream>>>(topk_idx, topk_prob, offsets, cursor, row_tok, row_prob);
    gemm1_kernel<<<dim3(HID / 128, 32, NEXP), dim3(256), 0, stream>>>(
        xbf, w1, b1, w2, b2, counts, offsets, row_tok, Hbuf);
    gemm2_kernel<<<dim3(EMB / 128, 32, NEXP), dim3(256), 0, stream>>>(
        Hbuf, w3, b3, counts, offsets, row_tok, row_prob, out);
}

// Round 2
// 856.268 us; speedup vs baseline: 1.6757x; 1.6757x over previous
//
#include <hip/hip_runtime.h>
#include <hip/hip_bf16.h>
#include <cstdint>
#include <cstddef>

#define NTOK 4096
#define EMB 1024
#define HID 4096
#define NEXP 8
#define LDP 40          // fallback-path LDS stride (padded)
#define RTR_BLOCKS 256  // router blocks (16 tokens each)

typedef __bf16 bf16x8_t __attribute__((ext_vector_type(8)));
typedef __bf16 bf16x4_t __attribute__((ext_vector_type(4)));
typedef float  f32x4_t  __attribute__((ext_vector_type(4)));

// async 16B global->LDS (direct-to-LDS DMA; LDS dest = wave-uniform base + lane*16)
__device__ __forceinline__ void gll16(const void* g, void* l) {
    __builtin_amdgcn_global_load_lds(
        (const __attribute__((address_space(1))) void*)g,
        (__attribute__((address_space(3))) void*)l, 16, 0, 0);
}

// ---------------- router: scores, top-2, softmax; per-block partials (NO global atomics) ----------------
__global__ __launch_bounds__(256) void router_kernel(
    const float* __restrict__ x, const float* __restrict__ gw,
    int* __restrict__ topk_idx, float* __restrict__ topk_prob,
    int* __restrict__ pcount, float* __restrict__ pprob)
{
    __shared__ int cs[8];
    __shared__ float ps[8];
    const int tid = threadIdx.x;
    if (tid < 8) { cs[tid] = 0; ps[tid] = 0.f; }
    __syncthreads();
    const int lane = tid & 63, wave = tid >> 6;
#pragma unroll
    for (int it = 0; it < 4; ++it) {
        const int t = blockIdx.x * 16 + wave * 4 + it;
        const float* xr = x + (size_t)t * EMB;
        float xv[16];
#pragma unroll
        for (int i = 0; i < 16; i++) xv[i] = xr[lane + 64 * i];
        float sc[8];
#pragma unroll
        for (int e = 0; e < 8; e++) {
            const float* g = gw + (size_t)e * EMB;
            float a = 0.f;
#pragma unroll
            for (int i = 0; i < 16; i++) a += xv[i] * g[lane + 64 * i];
            sc[e] = a;
        }
#pragma unroll
        for (int off = 32; off; off >>= 1)
#pragma unroll
            for (int e = 0; e < 8; e++) sc[e] += __shfl_xor(sc[e], off, 64);
        if (lane == 0) {
            int j0 = 0; float s0 = sc[0];
            for (int e = 1; e < 8; e++) if (sc[e] > s0) { s0 = sc[e]; j0 = e; }
            int j1 = -1; float s1 = -1e30f;
            for (int e = 0; e < 8; e++) if (e != j0 && sc[e] > s1) { s1 = sc[e]; j1 = e; }
            float r = __expf(s1 - s0);
            float p0 = 1.0f / (1.0f + r);
            float p1 = r * p0;
            topk_idx[2 * t] = j0;  topk_idx[2 * t + 1] = j1;
            topk_prob[2 * t] = p0; topk_prob[2 * t + 1] = p1;
            atomicAdd(&cs[j0], 1);   // LDS atomics: cheap
            atomicAdd(&cs[j1], 1);
            float pe[8]; float sum = 0.f;
            for (int e = 0; e < 8; e++) { pe[e] = __expf(sc[e] - s0); sum += pe[e]; }
            float inv = 1.0f / sum;
            for (int e = 0; e < 8; e++) atomicAdd(&ps[e], pe[e] * inv);
        }
    }
    __syncthreads();
    if (tid < 8) {
        pcount[blockIdx.x * 8 + tid] = cs[tid];
        pprob[blockIdx.x * 8 + tid]  = ps[tid];
    }
}

// ---------------- scan: reduce partials -> counts/offsets + aux loss ----------------
__global__ void scan_kernel(const int* __restrict__ pcount, const float* __restrict__ pprob,
                            int* __restrict__ counts, int* __restrict__ offsets,
                            float* __restrict__ aux_out)
{
    __shared__ int cs[8]; __shared__ float ps[8];
    const int tid = threadIdx.x;
    if (tid < 8) {
        int c = 0; float p = 0.f;
        for (int b = 0; b < RTR_BLOCKS; ++b) { c += pcount[b * 8 + tid]; p += pprob[b * 8 + tid]; }
        counts[tid] = c; cs[tid] = c; ps[tid] = p;
    }
    __syncthreads();
    if (tid == 0) {
        int off = 0; float aux = 0.f;
        for (int e = 0; e < 8; e++) { offsets[e] = off; off += cs[e]; aux += (float)cs[e] * ps[e]; }
        *aux_out = aux * 8.0f / ((float)NTOK * (float)NTOK);
    }
}

// ---------------- scatter: ballot-aggregated cursor atomics ----------------
__global__ __launch_bounds__(256) void scatter_kernel(
    const int* __restrict__ topk_idx, const float* __restrict__ topk_prob,
    const int* __restrict__ offsets, int* __restrict__ cursor,
    int* __restrict__ row_tok, float* __restrict__ row_prob)
{
    const int t = blockIdx.x * 256 + threadIdx.x;
    const int lane = threadIdx.x & 63;
    const unsigned long long mylt = (lane == 63) ? 0x7fffffffffffffffull : ((1ull << lane) - 1ull);
#pragma unroll
    for (int k = 0; k < 2; k++) {
        const int e = topk_idx[2 * t + k];
        const float p = topk_prob[2 * t + k];
        int base = 0;
        for (int ex = 0; ex < 8; ++ex) {
            unsigned long long m = __ballot(e == ex);
            if (m) {
                int leader = __ffsll((long long)m) - 1;
                int b = 0;
                if (lane == leader) b = atomicAdd(&cursor[ex], (int)__popcll(m));
                b = __shfl(b, leader, 64);
                if (e == ex) base = b + (int)__popcll(m & mylt);
            }
        }
        const int pos = offsets[e] + base;
        row_tok[pos] = t;
        row_prob[pos] = p;
    }
}

// ---------------- fp32 -> bf16 pack (8 elems/thread) ----------------
__global__ void cvt_pack(const float* __restrict__ src, __bf16* __restrict__ dst, int n8)
{
    const int i = blockIdx.x * 256 + threadIdx.x;
    if (i >= n8) return;
    const float4* s = (const float4*)src + (size_t)i * 2;
    float4 u = s[0], v = s[1];
    bf16x8_t o;
    o[0] = (__bf16)u.x; o[1] = (__bf16)u.y; o[2] = (__bf16)u.z; o[3] = (__bf16)u.w;
    o[4] = (__bf16)v.x; o[5] = (__bf16)v.y; o[6] = (__bf16)v.z; o[7] = (__bf16)v.w;
    *(bf16x8_t*)(dst + (size_t)i * 8) = o;
}

// ================= FAST PATH: bf16 weights + global_load_lds staging =================

// GEMM1: H = silu(Xg W1^T + b1) * (Xg W2^T + b2)
__global__ __launch_bounds__(256, 2) void gemm1_bf(
    const __bf16* __restrict__ xbf,
    const __bf16* __restrict__ w1bf, const float* __restrict__ b1,
    const __bf16* __restrict__ w2bf, const float* __restrict__ b2,
    const int* __restrict__ counts, const int* __restrict__ offsets,
    const int* __restrict__ row_tok, __bf16* __restrict__ Hbuf)
{
    const int e = blockIdx.z;
    const int cnt = counts[e];
    const int row0 = blockIdx.y * 128;
    if (row0 >= cnt) return;
    const int seg = offsets[e];
    const int n0 = blockIdx.x * 128;

    __shared__ __align__(16) __bf16 As[128 * 32];
    __shared__ __align__(16) __bf16 Bs1[128 * 32];
    __shared__ __align__(16) __bf16 Bs2[128 * 32];

    const int tid = threadIdx.x;
    const int lane = tid & 63;
    const int wave = tid >> 6;
    const int c4 = lane & 3;       // 16B chunk within 64B row
    const int r16 = lane >> 2;     // row within 16-row group
    const int ra0 = wave * 32 + r16;
    const int ra1 = ra0 + 16;

    // A gather: per-lane token row (clamp OOB rows to a valid index; garbage rows masked in epilogue)
    int ia0 = seg + row0 + ra0; if (ia0 > 8191) ia0 = 8191;
    int ia1 = seg + row0 + ra1; if (ia1 > 8191) ia1 = 8191;
    const __bf16* a0p = xbf + (size_t)row_tok[ia0] * EMB + c4 * 8;
    const __bf16* a1p = xbf + (size_t)row_tok[ia1] * EMB + c4 * 8;
    const __bf16* b10p = w1bf + ((size_t)e * HID + n0 + ra0) * EMB + c4 * 8;
    const __bf16* b11p = w1bf + ((size_t)e * HID + n0 + ra1) * EMB + c4 * 8;
    const __bf16* b20p = w2bf + ((size_t)e * HID + n0 + ra0) * EMB + c4 * 8;
    const __bf16* b21p = w2bf + ((size_t)e * HID + n0 + ra1) * EMB + c4 * 8;

    // wave-uniform LDS bases (rows of 32 bf16 = 64B; 16 rows = 1KB per instruction)
    __bf16* lA0 = &As [(wave * 32) * 32];
    __bf16* lA1 = &As [(wave * 32 + 16) * 32];
    __bf16* lB10 = &Bs1[(wave * 32) * 32];
    __bf16* lB11 = &Bs1[(wave * 32 + 16) * 32];
    __bf16* lB20 = &Bs2[(wave * 32) * 32];
    __bf16* lB21 = &Bs2[(wave * 32 + 16) * 32];

    const int fr = lane & 15;
    const int quad = lane >> 4;
    const int wm = (wave >> 1) * 64;
    const int wn = (wave & 1) * 64;

    f32x4_t acc1[4][4], acc2[4][4];
#pragma unroll
    for (int i = 0; i < 4; i++)
#pragma unroll
        for (int j = 0; j < 4; j++)
#pragma unroll
            for (int c = 0; c < 4; c++) { acc1[i][j][c] = 0.f; acc2[i][j][c] = 0.f; }

    for (int kk = 0; kk < EMB / 32; ++kk) {
        __syncthreads();                 // previous fragments consumed
        gll16(a0p, lA0);  gll16(a1p, lA1);
        gll16(b10p, lB10); gll16(b11p, lB11);
        gll16(b20p, lB20); gll16(b21p, lB21);
        a0p += 32; a1p += 32; b10p += 32; b11p += 32; b20p += 32; b21p += 32;
        __syncthreads();                 // drains vmcnt -> staging visible

        bf16x8_t av[4], bv1[4], bv2[4];
#pragma unroll
        for (int i = 0; i < 4; i++) av[i]  = *(const bf16x8_t*)&As [(wm + i * 16 + fr) * 32 + quad * 8];
#pragma unroll
        for (int j = 0; j < 4; j++) bv1[j] = *(const bf16x8_t*)&Bs1[(wn + j * 16 + fr) * 32 + quad * 8];
#pragma unroll
        for (int j = 0; j < 4; j++) bv2[j] = *(const bf16x8_t*)&Bs2[(wn + j * 16 + fr) * 32 + quad * 8];
#pragma unroll
        for (int i = 0; i < 4; i++)
#pragma unroll
            for (int j = 0; j < 4; j++) {
                acc1[i][j] = __builtin_amdgcn_mfma_f32_16x16x32_bf16(av[i], bv1[j], acc1[i][j], 0, 0, 0);
                acc2[i][j] = __builtin_amdgcn_mfma_f32_16x16x32_bf16(av[i], bv2[j], acc2[i][j], 0, 0, 0);
            }
    }

    float b1v[4], b2v[4];
#pragma unroll
    for (int j = 0; j < 4; j++) {
        int nn = n0 + wn + j * 16 + fr;
        b1v[j] = b1[(size_t)e * HID + nn];
        b2v[j] = b2[(size_t)e * HID + nn];
    }
#pragma unroll
    for (int i = 0; i < 4; i++) {
#pragma unroll
        for (int rr = 0; rr < 4; rr++) {
            int grow = row0 + wm + i * 16 + quad * 4 + rr;
            if (grow < cnt) {
                __bf16* hrow = Hbuf + (size_t)(seg + grow) * HID;
#pragma unroll
                for (int j = 0; j < 4; j++) {
                    float c1 = acc1[i][j][rr] + b1v[j];
                    float c2 = acc2[i][j][rr] + b2v[j];
                    float sig = 1.0f / (1.0f + __expf(-c1));
                    hrow[n0 + wn + j * 16 + fr] = (__bf16)(c1 * sig * c2);
                }
            }
        }
    }
}

// GEMM2: out += p * (H W3^T + b3)
__global__ __launch_bounds__(256, 2) void gemm2_bf(
    const __bf16* __restrict__ Hbuf,
    const __bf16* __restrict__ w3bf, const float* __restrict__ b3,
    const int* __restrict__ counts, const int* __restrict__ offsets,
    const int* __restrict__ row_tok, const float* __restrict__ row_prob,
    float* __restrict__ out)
{
    const int e = blockIdx.z;
    const int cnt = counts[e];
    const int row0 = blockIdx.y * 128;
    if (row0 >= cnt) return;
    const int seg = offsets[e];
    const int n0 = blockIdx.x * 128;

    __shared__ __align__(16) __bf16 As[128 * 32];
    __shared__ __align__(16) __bf16 Bs[128 * 32];

    const int tid = threadIdx.x;
    const int lane = tid & 63;
    const int wave = tid >> 6;
    const int c4 = lane & 3;
    const int r16 = lane >> 2;
    const int ra0 = wave * 32 + r16;
    const int ra1 = ra0 + 16;

    // Hbuf rows are contiguous (slack rows allocated; garbage rows masked in epilogue)
    const __bf16* a0p = Hbuf + (size_t)(seg + row0 + ra0) * HID + c4 * 8;
    const __bf16* a1p = Hbuf + (size_t)(seg + row0 + ra1) * HID + c4 * 8;
    const __bf16* b0p = w3bf + ((size_t)e * EMB + n0 + ra0) * HID + c4 * 8;
    const __bf16* b1p = w3bf + ((size_t)e * EMB + n0 + ra1) * HID + c4 * 8;

    __bf16* lA0 = &As[(wave * 32) * 32];
    __bf16* lA1 = &As[(wave * 32 + 16) * 32];
    __bf16* lB0 = &Bs[(wave * 32) * 32];
    __bf16* lB1 = &Bs[(wave * 32 + 16) * 32];

    const int fr = lane & 15;
    const int quad = lane >> 4;
    const int wm = (wave >> 1) * 64;
    const int wn = (wave & 1) * 64;

    f32x4_t acc[4][4];
#pragma unroll
    for (int i = 0; i < 4; i++)
#pragma unroll
        for (int j = 0; j < 4; j++)
#pragma unroll
            for (int c = 0; c < 4; c++) acc[i][j][c] = 0.f;

    for (int kk = 0; kk < HID / 32; ++kk) {
        __syncthreads();
        gll16(a0p, lA0); gll16(a1p, lA1);
        gll16(b0p, lB0); gll16(b1p, lB1);
        a0p += 32; a1p += 32; b0p += 32; b1p += 32;
        __syncthreads();

        bf16x8_t av[4], bv[4];
#pragma unroll
        for (int i = 0; i < 4; i++) av[i] = *(const bf16x8_t*)&As[(wm + i * 16 + fr) * 32 + quad * 8];
#pragma unroll
        for (int j = 0; j < 4; j++) bv[j] = *(const bf16x8_t*)&Bs[(wn + j * 16 + fr) * 32 + quad * 8];
#pragma unroll
        for (int i = 0; i < 4; i++)
#pragma unroll
            for (int j = 0; j < 4; j++)
                acc[i][j] = __builtin_amdgcn_mfma_f32_16x16x32_bf16(av[i], bv[j], acc[i][j], 0, 0, 0);
    }

    float b3v[4];
#pragma unroll
    for (int j = 0; j < 4; j++) b3v[j] = b3[(size_t)e * EMB + n0 + wn + j * 16 + fr];
#pragma unroll
    for (int i = 0; i < 4; i++) {
#pragma unroll
        for (int rr = 0; rr < 4; rr++) {
            int grow = row0 + wm + i * 16 + quad * 4 + rr;
            if (grow < cnt) {
                int tok = row_tok[seg + grow];
                float pr = row_prob[seg + grow];
                float* orow = out + (size_t)tok * EMB;
#pragma unroll
                for (int j = 0; j < 4; j++) {
                    float v = pr * (acc[i][j][rr] + b3v[j]);
                    atomicAdd(&orow[n0 + wn + j * 16 + fr], v);
                }
            }
        }
    }
}

// ================= FALLBACK PATH (fp32 weights staged through VGPRs) =================

__global__ __launch_bounds__(256, 2) void gemm1_f32(
    const __bf16* __restrict__ xbf,
    const float* __restrict__ w1, const float* __restrict__ b1,
    const float* __restrict__ w2, const float* __restrict__ b2,
    const int* __restrict__ counts, const int* __restrict__ offsets,
    const int* __restrict__ row_tok, __bf16* __restrict__ Hbuf)
{
    const int e = blockIdx.z;
    const int cnt = counts[e];
    const int row0 = blockIdx.y * 128;
    if (row0 >= cnt) return;
    const int seg = offsets[e];
    const int n0 = blockIdx.x * 128;

    __shared__ __align__(16) __bf16 As[128][LDP];
    __shared__ __align__(16) __bf16 Bs1[128][LDP];
    __shared__ __align__(16) __bf16 Bs2[128][LDP];

    const int tid = threadIdx.x;
    const int sr = tid >> 1;
    const int sh = tid & 1;

    const uint4* ap = nullptr;
    if (row0 + sr < cnt) {
        const int tok = row_tok[seg + row0 + sr];
        ap = (const uint4*)(xbf + (size_t)tok * EMB) + sh * 2;
    }
    const float4* b1p = (const float4*)(w1 + ((size_t)e * HID + n0 + sr) * EMB) + sh * 4;
    const float4* b2p = (const float4*)(w2 + ((size_t)e * HID + n0 + sr) * EMB) + sh * 4;

    const int lane = tid & 63;
    const int wave = tid >> 6;
    const int wm = (wave >> 1) * 64;
    const int wn = (wave & 1) * 64;
    const int fr = lane & 15;
    const int quad = lane >> 4;

    f32x4_t acc1[4][4], acc2[4][4];
#pragma unroll
    for (int i = 0; i < 4; i++)
#pragma unroll
        for (int j = 0; j < 4; j++)
#pragma unroll
            for (int c = 0; c < 4; c++) { acc1[i][j][c] = 0.f; acc2[i][j][c] = 0.f; }

    for (int kk = 0; kk < EMB; kk += 32) {
        uint4 a0 = {0,0,0,0}, a1 = {0,0,0,0};
        if (ap) { a0 = ap[0]; a1 = ap[1]; ap += 4; }
        float4 f10 = b1p[0], f11 = b1p[1], f12 = b1p[2], f13 = b1p[3]; b1p += 8;
        float4 f20 = b2p[0], f21 = b2p[1], f22 = b2p[2], f23 = b2p[3]; b2p += 8;

        __syncthreads();
        *(uint4*)&As[sr][sh * 16]     = a0;
        *(uint4*)&As[sr][sh * 16 + 8] = a1;
        bf16x8_t p;
        p[0]=(__bf16)f10.x; p[1]=(__bf16)f10.y; p[2]=(__bf16)f10.z; p[3]=(__bf16)f10.w;
        p[4]=(__bf16)f11.x; p[5]=(__bf16)f11.y; p[6]=(__bf16)f11.z; p[7]=(__bf16)f11.w;
        *(bf16x8_t*)&Bs1[sr][sh * 16] = p;
        p[0]=(__bf16)f12.x; p[1]=(__bf16)f12.y; p[2]=(__bf16)f12.z; p[3]=(__bf16)f12.w;
        p[4]=(__bf16)f13.x; p[5]=(__bf16)f13.y; p[6]=(__bf16)f13.z; p[7]=(__bf16)f13.w;
        *(bf16x8_t*)&Bs1[sr][sh * 16 + 8] = p;
        p[0]=(__bf16)f20.x; p[1]=(__bf16)f20.y; p[2]=(__bf16)f20.z; p[3]=(__bf16)f20.w;
        p[4]=(__bf16)f21.x; p[5]=(__bf16)f21.y; p[6]=(__bf16)f21.z; p[7]=(__bf16)f21.w;
        *(bf16x8_t*)&Bs2[sr][sh * 16] = p;
        p[0]=(__bf16)f22.x; p[1]=(__bf16)f22.y; p[2]=(__bf16)f22.z; p[3]=(__bf16)f22.w;
        p[4]=(__bf16)f23.x; p[5]=(__bf16)f23.y; p[6]=(__bf16)f23.z; p[7]=(__bf16)f23.w;
        *(bf16x8_t*)&Bs2[sr][sh * 16 + 8] = p;
        __syncthreads();

        bf16x8_t av[4], bv1[4], bv2[4];
#pragma unroll
        for (int i = 0; i < 4; i++) av[i]  = *(const bf16x8_t*)&As [wm + i * 16 + fr][quad * 8];
#pragma unroll
        for (int j = 0; j < 4; j++) bv1[j] = *(const bf16x8_t*)&Bs1[wn + j * 16 + fr][quad * 8];
#pragma unroll
        for (int j = 0; j < 4; j++) bv2[j] = *(const bf16x8_t*)&Bs2[wn + j * 16 + fr][quad * 8];
#pragma unroll
        for (int i = 0; i < 4; i++)
#pragma unroll
            for (int j = 0; j < 4; j++) {
                acc1[i][j] = __builtin_amdgcn_mfma_f32_16x16x32_bf16(av[i], bv1[j], acc1[i][j], 0, 0, 0);
                acc2[i][j] = __builtin_amdgcn_mfma_f32_16x16x32_bf16(av[i], bv2[j], acc2[i][j], 0, 0, 0);
            }
    }

    float b1v[4], b2v[4];
#pragma unroll
    for (int j = 0; j < 4; j++) {
        int nn = n0 + wn + j * 16 + fr;
        b1v[j] = b1[(size_t)e * HID + nn];
        b2v[j] = b2[(size_t)e * HID + nn];
    }
#pragma unroll
    for (int i = 0; i < 4; i++) {
#pragma unroll
        for (int rr = 0; rr < 4; rr++) {
            int grow = row0 + wm + i * 16 + quad * 4 + rr;
            if (grow < cnt) {
                __bf16* hrow = Hbuf + (size_t)(seg + grow) * HID;
#pragma unroll
                for (int j = 0; j < 4; j++) {
                    float c1 = acc1[i][j][rr] + b1v[j];
                    float c2 = acc2[i][j][rr] + b2v[j];
                    float sig = 1.0f / (1.0f + __expf(-c1));
                    hrow[n0 + wn + j * 16 + fr] = (__bf16)(c1 * sig * c2);
                }
            }
        }
    }
}

__global__ __launch_bounds__(256, 2) void gemm2_f32(
    const __bf16* __restrict__ Hbuf,
    const float* __restrict__ w3, const float* __restrict__ b3,
    const int* __restrict__ counts, const int* __restrict__ offsets,
    const int* __restrict__ row_tok, const float* __restrict__ row_prob,
    float* __restrict__ out)
{
    const int e = blockIdx.z;
    const int cnt = counts[e];
    const int row0 = blockIdx.y * 128;
    if (row0 >= cnt) return;
    const int seg = offsets[e];
    const int n0 = blockIdx.x * 128;

    __shared__ __align__(16) __bf16 As[128][LDP];
    __shared__ __align__(16) __bf16 Bs[128][LDP];

    const int tid = threadIdx.x;
    const int sr = tid >> 1;
    const int sh = tid & 1;

    const uint4* ap = (const uint4*)(Hbuf + (size_t)(seg + row0 + sr) * HID) + sh * 2;
    const float4* bp = (const float4*)(w3 + ((size_t)e * EMB + n0 + sr) * HID) + sh * 4;

    const int lane = tid & 63;
    const int wave = tid >> 6;
    const int wm = (wave >> 1) * 64;
    const int wn = (wave & 1) * 64;
    const int fr = lane & 15;
    const int quad = lane >> 4;

    f32x4_t acc[4][4];
#pragma unroll
    for (int i = 0; i < 4; i++)
#pragma unroll
        for (int j = 0; j < 4; j++)
#pragma unroll
            for (int c = 0; c < 4; c++) acc[i][j][c] = 0.f;

    for (int kk = 0; kk < HID; kk += 32) {
        uint4 a0 = ap[0], a1 = ap[1]; ap += 4;
        float4 f0 = bp[0], f1 = bp[1], f2 = bp[2], f3 = bp[3]; bp += 8;

        __syncthreads();
        *(uint4*)&As[sr][sh * 16]     = a0;
        *(uint4*)&As[sr][sh * 16 + 8] = a1;
        bf16x8_t p;
        p[0]=(__bf16)f0.x; p[1]=(__bf16)f0.y; p[2]=(__bf16)f0.z; p[3]=(__bf16)f0.w;
        p[4]=(__bf16)f1.x; p[5]=(__bf16)f1.y; p[6]=(__bf16)f1.z; p[7]=(__bf16)f1.w;
        *(bf16x8_t*)&Bs[sr][sh * 16] = p;
        p[0]=(__bf16)f2.x; p[1]=(__bf16)f2.y; p[2]=(__bf16)f2.z; p[3]=(__bf16)f2.w;
        p[4]=(__bf16)f3.x; p[5]=(__bf16)f3.y; p[6]=(__bf16)f3.z; p[7]=(__bf16)f3.w;
        *(bf16x8_t*)&Bs[sr][sh * 16 + 8] = p;
        __syncthreads();

        bf16x8_t av[4], bv[4];
#pragma unroll
        for (int i = 0; i < 4; i++) av[i] = *(const bf16x8_t*)&As[wm + i * 16 + fr][quad * 8];
#pragma unroll
        for (int j = 0; j < 4; j++) bv[j] = *(const bf16x8_t*)&Bs[wn + j * 16 + fr][quad * 8];
#pragma unroll
        for (int i = 0; i < 4; i++)
#pragma unroll
            for (int j = 0; j < 4; j++)
                acc[i][j] = __builtin_amdgcn_mfma_f32_16x16x32_bf16(av[i], bv[j], acc[i][j], 0, 0, 0);
    }

    float b3v[4];
#pragma unroll
    for (int j = 0; j < 4; j++) b3v[j] = b3[(size_t)e * EMB + n0 + wn + j * 16 + fr];
#pragma unroll
    for (int i = 0; i < 4; i++) {
#pragma unroll
        for (int rr = 0; rr < 4; rr++) {
            int grow = row0 + wm + i * 16 + quad * 4 + rr;
            if (grow < cnt) {
                int tok = row_tok[seg + grow];
                float pr = row_prob[seg + grow];
                float* orow = out + (size_t)tok * EMB;
#pragma unroll
                for (int j = 0; j < 4; j++) {
                    float v = pr * (acc[i][j][rr] + b3v[j]);
                    atomicAdd(&orow[n0 + wn + j * 16 + fr], v);
                }
            }
        }
    }
}

extern "C" void kernel_launch(void* const* d_in, const int* in_sizes, int n_in,
                              void* d_out, int out_size, void* d_ws, size_t ws_size,
                              hipStream_t stream)
{
    const float* x  = (const float*)d_in[0];
    const float* gw = (const float*)d_in[1];
    const float* w1 = (const float*)d_in[2];
    const float* b1 = (const float*)d_in[3];
    const float* w2 = (const float*)d_in[4];
    const float* b2 = (const float*)d_in[5];
    const float* w3 = (const float*)d_in[6];
    const float* b3 = (const float*)d_in[7];
    float* out = (float*)d_out;

    char* ws = (char*)d_ws;
    int*   counts    = (int*)(ws + 0);
    int*   offsets   = (int*)(ws + 32);
    int*   cursor    = (int*)(ws + 64);
    int*   topk_idx  = (int*)(ws + 1024);
    float* topk_prob = (float*)(ws + 1024 + 32768);
    int*   row_tok   = (int*)(ws + 1024 + 65536);
    float* row_prob  = (float*)(ws + 1024 + 98304);
    int*   pcount    = (int*)(ws + 1024 + 131072);
    float* pprob     = (float*)(ws + 1024 + 131072 + 8192);
    __bf16* xbf  = (__bf16*)(ws + (1u << 20));            // 8.39 MB
    __bf16* Hbuf = (__bf16*)(ws + (16u << 20));           // (8192+128)*4096*2 = 68.2 MB
    __bf16* w1bf = (__bf16*)(ws + 88080384ull);           // 67.1 MB
    __bf16* w2bf = (__bf16*)(ws + 157286400ull);          // 67.1 MB, ends 224,395,264
    __bf16* w3bf = w1bf;                                  // reused after gemm1 completes
    const size_t NEED_FAST = 224395264ull;

    hipMemsetAsync(ws, 0, 1024, stream);
    hipMemsetAsync(d_out, 0, (size_t)out_size * sizeof(float), stream);

    router_kernel<<<dim3(RTR_BLOCKS), dim3(256), 0, stream>>>(x, gw, topk_idx, topk_prob, pcount, pprob);
    scan_kernel<<<dim3(1), dim3(64), 0, stream>>>(pcount, pprob, counts, offsets, out + (size_t)NTOK * EMB);
    scatter_kernel<<<dim3(NTOK / 256), dim3(256), 0, stream>>>(topk_idx, topk_prob, offsets, cursor, row_tok, row_prob);
    cvt_pack<<<dim3((NTOK * EMB / 8) / 256), dim3(256), 0, stream>>>(x, xbf, NTOK * EMB / 8);

    if (ws_size >= NEED_FAST) {
        const int wn8 = NEXP * HID * EMB / 8;   // 4,194,304
        cvt_pack<<<dim3(wn8 / 256), dim3(256), 0, stream>>>(w1, w1bf, wn8);
        cvt_pack<<<dim3(wn8 / 256), dim3(256), 0, stream>>>(w2, w2bf, wn8);
        gemm1_bf<<<dim3(HID / 128, 32, NEXP), dim3(256), 0, stream>>>(
            xbf, w1bf, b1, w2bf, b2, counts, offsets, row_tok, Hbuf);
        cvt_pack<<<dim3(wn8 / 256), dim3(256), 0, stream>>>(w3, w3bf, wn8);
        gemm2_bf<<<dim3(EMB / 128, 32, NEXP), dim3(256), 0, stream>>>(
            Hbuf, w3bf, b3, counts, offsets, row_tok, row_prob, out);
    } else {
        gemm1_f32<<<dim3(HID / 128, 32, NEXP), dim3(256), 0, stream>>>(
            xbf, w1, b1, w2, b2, counts, offsets, row_tok, Hbuf);
        gemm2_f32<<<dim3(EMB / 128, 32, NEXP), dim3(256), 0, stream>>>(
            Hbuf, w3, b3, counts, offsets, row_tok, row_prob, out);
    }
}